// Round 13
// baseline (78.320 us; speedup 1.0000x reference)
//
#include <hip/hip_runtime.h>
#include <math.h>

#define C_ 512
#define HW_ 16384
#define K_ 19
#define M_ 5
#define P_ 95
#define P2 96
#define TPX 32
#define GRID_ 1024
#define TILES_ 2
#define HL2PI 470.49652900081467f  // 0.5 * 512 * ln(2*pi)

typedef __attribute__((ext_vector_type(8))) short short8;
typedef __attribute__((ext_vector_type(4))) int int4v;
typedef __attribute__((ext_vector_type(4))) float float4v;

// fp32 -> bf16 RNE (prep kernel only; main uses packed cvt)
static __device__ __forceinline__ short f2bf(float f) {
  unsigned u = __builtin_bit_cast(unsigned, f);
  unsigned r = (u + 0x7fffu + ((u >> 16) & 1u)) >> 16;
  return (short)r;
}
static __device__ __forceinline__ float bf2f(short s) {
  return __builtin_bit_cast(float, ((unsigned)(unsigned short)s) << 16);
}

// pack 2 floats -> bf16x2 via v_cvt_pk_bf16_f32 (no builtin on gfx950)
static __device__ __forceinline__ int pk2(float a, float b) {
  int r;
  asm("v_cvt_pk_bf16_f32 %0, %1, %2" : "=v"(r) : "v"(a), "v"(b));
  return r;
}

// square a bf16x8 fragment in-register: unpack pairs, square, packed-repack
static __device__ __forceinline__ short8 sq8(short8 a) {
  int4v ai = __builtin_bit_cast(int4v, a);
  int4v ri;
#pragma unroll
  for (int j = 0; j < 4; j++) {
    unsigned u = (unsigned)ai[j];
    float lo = __builtin_bit_cast(float, u << 16);
    float hi = __builtin_bit_cast(float, u & 0xffff0000u);
    ri[j] = pk2(lo * lo, hi * hi);
  }
  return __builtin_bit_cast(short8, ri);
}

__device__ __forceinline__ float block_reduce_sum(float v, volatile float* red) {
#pragma unroll
  for (int o = 32; o; o >>= 1) v += __shfl_down(v, o);
  const int lane = threadIdx.x & 63, wv = threadIdx.x >> 6;
  if (lane == 0) red[wv] = v;
  __syncthreads();
  float r = red[0] + red[1] + red[2] + red[3];
  __syncthreads();
  return r;
}

// One block per prototype p. wbf[p][k] bf16 row-major [96][1024]:
//   k <  512: inv_var[c];  k >= 512: mu[c]*inv_var[c]
// cterm[p] = -0.5*q3 - logdet - HL2PI  (fp32)
__global__ __launch_bounds__(256) void prep_kernel(
    const float* __restrict__ means, const float* __restrict__ diag,
    short* __restrict__ wbf, float* __restrict__ cterm) {
  const int p = blockIdx.x;
  const int tid = threadIdx.x;
  __shared__ float red[4];
  if (p >= P_) {  // zero-pad row 95: contributes 0, never selected in max
    for (int c = tid; c < C_; c += 256) {
      wbf[p * 1024 + c] = 0;
      wbf[p * 1024 + 512 + c] = 0;
    }
    if (tid == 0) cterm[p] = 0.f;
    return;
  }
  const float* mrow = means + (size_t)p * C_;
  const float* srow = diag + (size_t)p * C_;
  float m0 = mrow[tid], m1 = mrow[tid + 256];
  float ss = block_reduce_sum(m0 * m0 + m1 * m1, red);
  float rden = 1.f / fmaxf(sqrtf(ss), 1e-12f);  // l2_normalize(means)
  float q3 = 0.f, ld = 0.f;
#pragma unroll
  for (int t = 0; t < 2; t++) {
    int c = tid + t * 256;
    float m = mrow[c], s = srow[c];
    float mu = m * rden;
    float iv = 1.f / (s * s);
    wbf[p * 1024 + c] = f2bf(iv);
    wbf[p * 1024 + 512 + c] = f2bf(mu * iv);
    q3 += mu * mu * iv;
    ld += logf(s);
  }
  q3 = block_reduce_sum(q3, red);
  ld = block_reduce_sum(ld, red);
  if (tid == 0) cterm[p] = -0.5f * q3 - ld - HL2PI;
}

// Persistent: 1024 blocks x 2 tiles of 32 pixels (4 blocks/CU, LDS 39.4 KB).
// Tile pipeline (T14 async-stage): tile t+1's 16 float4 x-loads are issued
// right after tile t's pack phase; they ride in registers under
// stats+RMW+MFMA+epilogue. NO global reads occur between issue and consume
// (fg/fb/cterm/mg/mb staged in LDS; in-order vmem retirement would force a
// drain otherwise). MFMA wbf loads come >2 barriers later - prefetch retired.
// Per-tile structure, layouts and numerics are verbatim R12 (absmax-verified).
__global__ __launch_bounds__(256, 4) void main_kernel(
    const float* __restrict__ x,
    const float* __restrict__ fg, const float* __restrict__ fb,
    const float* __restrict__ mg, const float* __restrict__ mb,
    const short* __restrict__ wbf, const float* __restrict__ cterm,
    float* __restrict__ out) {
  __shared__ __align__(16) char raw[32768];  // x/v frags; then lp[32][100] + mpr @16384
  __shared__ float redS[128], redQ[128];     // 32 slots x float4
  __shared__ float meanA[TPX], rstdA[TPX], rnA[TPX], rn2A[TPX];
  __shared__ float mean2A[TPX], rstd2A[TPX];
  __shared__ float fgs[C_], fbs[C_], cts[P2], mgs[K_ + 1], mbs[K_ + 1];

  const int tid = threadIdx.x;
  const int wv = tid >> 6, lane = tid & 63;
  const int cg = tid >> 3, q = tid & 7;  // channel group (16c), pixel quad
  const int c16 = cg * 16;
  const int blkw = (q >> 2) * 16 + (cg >> 1);
  const int sbase = (q & 3) * 2 + (cg & 1);

  // ---- prologue: stage all small params into LDS ----
  for (int i = tid; i < C_; i += 256) { fgs[i] = fg[i]; fbs[i] = fb[i]; }
  if (tid < P2) cts[tid] = cterm[tid];
  if (tid < K_) { mgs[tid] = mg[tid]; mbs[tid] = mb[tid]; }

  float4v pf[16];
  {  // issue tile-0 x-loads
    const int n0 = blockIdx.x * TILES_ * TPX;
    const int b0 = n0 >> 14, rem = n0 & 16383, h0 = rem >> 7, w00 = rem & 127;
    const float* xp4 = x + (size_t)b0 * C_ * HW_ + h0 * 128 + w00 + q * 4;
#pragma unroll
    for (int i = 0; i < 16; i++)
      pf[i] = *(const float4v*)(xp4 + (size_t)(c16 + i) * HW_);
  }

#pragma unroll
  for (int t = 0; t < TILES_; ++t) {
    const int n0 = (blockIdx.x * TILES_ + t) * TPX;
    const int b = n0 >> 14;
    const int rem = n0 & 16383;
    const int h = rem >> 7;
    const int w0 = rem & 127;

    // ---- Phase A: consume pf (the only vmcnt wait), stats, x-frags -> LDS ----
    {
      float4v s4 = {0.f, 0.f, 0.f, 0.f}, q4 = {0.f, 0.f, 0.f, 0.f};
#pragma unroll
      for (int i = 0; i < 16; i++) {
        s4 += pf[i];
        q4 += pf[i] * pf[i];
      }
#pragma unroll
      for (int hc = 0; hc < 2; hc++) {
#pragma unroll
        for (int r = 0; r < 4; r++) {
          int4v pk;
#pragma unroll
          for (int j2 = 0; j2 < 4; j2++)
            pk[j2] = pk2(pf[hc * 8 + 2 * j2][r], pf[hc * 8 + 2 * j2 + 1][r]);
          *(int4v*)(raw + blkw * 1024 + ((hc * 4 + r) * 8 + sbase) * 16) = pk;
        }
      }
#pragma unroll
      for (int o = 8; o < 64; o <<= 1) {
#pragma unroll
        for (int c = 0; c < 4; c++) {
          s4[c] += __shfl_down(s4[c], o);
          q4[c] += __shfl_down(q4[c], o);
        }
      }
      if (lane < 8) {
        *(float4v*)(redS + (wv * 8 + lane) * 4) = s4;
        *(float4v*)(redQ + (wv * 8 + lane) * 4) = q4;
      }
    }

    // ---- issue next tile's x-loads NOW (hidden under the rest of this tile) ----
    if (t + 1 < TILES_) {
      const int n0n = (blockIdx.x * TILES_ + t + 1) * TPX;
      const int bn = n0n >> 14, remn = n0n & 16383, hn = remn >> 7, w0n = remn & 127;
      const float* xp4n = x + (size_t)bn * C_ * HW_ + hn * 128 + w0n + q * 4;
#pragma unroll
      for (int i = 0; i < 16; i++)
        pf[i] = *(const float4v*)(xp4n + (size_t)(c16 + i) * HW_);
    }
    __builtin_amdgcn_sched_barrier(0);  // pin the issue point above the barrier

    __syncthreads();
    if (tid < 32) {  // px = tid: q' = tid>>2, comp = tid&3
      float ss = 0.f, qq = 0.f;
#pragma unroll
      for (int w = 0; w < 4; w++) {
        ss += redS[(w * 8 + (tid >> 2)) * 4 + (tid & 3)];
        qq += redQ[(w * 8 + (tid >> 2)) * 4 + (tid & 3)];
      }
      float mean = ss * (1.f / C_);
      float var = qq * (1.f / C_) - mean * mean;
      meanA[tid] = mean;
      rstdA[tid] = rsqrtf(var + 1e-5f);
    }
    __syncthreads();

    // ---- Phase B: in-place LDS RMW x -> v = LN(x)*g+b; Sum v^2 (params from LDS) ----
    {
      float fga[16], fba[16];
#pragma unroll
      for (int i = 0; i < 4; i++) {
        *(float4v*)(fga + i * 4) = *(const float4v*)(fgs + c16 + i * 4);
        *(float4v*)(fba + i * 4) = *(const float4v*)(fbs + c16 + i * 4);
      }
      const float4v mean4 = *(const float4v*)(meanA + q * 4);
      const float4v rstd4 = *(const float4v*)(rstdA + q * 4);
      float4v s2 = {0.f, 0.f, 0.f, 0.f};
#pragma unroll
      for (int hc = 0; hc < 2; hc++) {
#pragma unroll
        for (int r = 0; r < 4; r++) {
          char* ad = raw + blkw * 1024 + ((hc * 4 + r) * 8 + sbase) * 16;
          short8 xc = *(short8*)ad;
          const float m = mean4[r], sd = rstd4[r];
          float vv[8];
#pragma unroll
          for (int j = 0; j < 8; j++) {
            float v = fmaf((bf2f(xc[j]) - m) * sd, fga[hc * 8 + j], fba[hc * 8 + j]);
            s2[r] = fmaf(v, v, s2[r]);
            vv[j] = v;
          }
          int4v pk;
#pragma unroll
          for (int j2 = 0; j2 < 4; j2++) pk[j2] = pk2(vv[2 * j2], vv[2 * j2 + 1]);
          *(int4v*)ad = pk;
        }
      }
#pragma unroll
      for (int o = 8; o < 64; o <<= 1) {
#pragma unroll
        for (int c = 0; c < 4; c++) s2[c] += __shfl_down(s2[c], o);
      }
      if (lane < 8) *(float4v*)(redS + (wv * 8 + lane) * 4) = s2;
    }
    __syncthreads();
    if (tid < 32) {
      float ss = 0.f;
#pragma unroll
      for (int w = 0; w < 4; w++) ss += redS[(w * 8 + (tid >> 2)) * 4 + (tid & 3)];
      float rn = 1.f / fmaxf(sqrtf(ss), 1e-12f);  // l2_normalize folded into epilogue
      rnA[tid] = rn;
      rn2A[tid] = rn * rn;
    }
    __syncthreads();

    // ---- MFMA: wave = (khalf = wv>>1, phalf = wv&1), 3 p-tiles x 2 px-tiles ----
    const int pbase = (wv & 1) * 3;
    const int khalf = wv >> 1;
    const int lm = lane & 15, lk = lane >> 4;
    const int slotR =
        ((((lane >> 4) & 1) * 4 + (lane & 3)) * 8 + ((lane >> 2) & 3) * 2 + ((lane >> 5) & 1)) * 16;
    float4v acc[3][2] = {{}, {}, {}};
    const short* wrow = wbf + (((pbase * 16 + lm) << 10) + (khalf << 9) + (lk << 3));
#pragma unroll 4
    for (int ksl = 0; ksl < 16; ksl++) {
      short8 a0 = *(const short8*)(wrow + ksl * 32);
      short8 a1 = *(const short8*)(wrow + 16384 + ksl * 32);
      short8 a2 = *(const short8*)(wrow + 32768 + ksl * 32);
      short8 b0 = *(const short8*)(raw + ksl * 1024 + slotR);
      short8 b1 = *(const short8*)(raw + (16 + ksl) * 1024 + slotR);
      if (khalf == 0) {  // wave-uniform branch
        b0 = sq8(b0);
        b1 = sq8(b1);
      }
      acc[0][0] = __builtin_amdgcn_mfma_f32_16x16x32_bf16(a0, b0, acc[0][0], 0, 0, 0);
      acc[0][1] = __builtin_amdgcn_mfma_f32_16x16x32_bf16(a0, b1, acc[0][1], 0, 0, 0);
      acc[1][0] = __builtin_amdgcn_mfma_f32_16x16x32_bf16(a1, b0, acc[1][0], 0, 0, 0);
      acc[1][1] = __builtin_amdgcn_mfma_f32_16x16x32_bf16(a1, b1, acc[1][1], 0, 0, 0);
      acc[2][0] = __builtin_amdgcn_mfma_f32_16x16x32_bf16(a2, b0, acc[2][0], 0, 0, 0);
      acc[2][1] = __builtin_amdgcn_mfma_f32_16x16x32_bf16(a2, b1, acc[2][1], 0, 0, 0);
    }
    __syncthreads();  // u dead; alias raw: lp[32][100], mpr @ raw+16384
    float* lp = (float*)raw;
    float* mpr = (float*)(raw + 16384);

    // stage 1: khalf0 waves write -0.5*rn2*q1 + ct  (cts from LDS)
    if (khalf == 0) {
#pragma unroll
      for (int i = 0; i < 3; i++) {
        const int prow = (pbase + i) * 16 + lk * 4;
#pragma unroll
        for (int r = 0; r < 4; r++) {
          const float ct = cts[prow + r];
#pragma unroll
          for (int t2 = 0; t2 < 2; t2++) {
            const int pxx = t2 * 16 + lm;
            lp[pxx * 100 + prow + r] = fmaf(-0.5f * rn2A[pxx], acc[i][t2][r], ct);
          }
        }
      }
    }
    __syncthreads();
    // stage 2: khalf1 waves add rn*q2
    if (khalf == 1) {
#pragma unroll
      for (int i = 0; i < 3; i++) {
        const int prow = (pbase + i) * 16 + lk * 4;
#pragma unroll
        for (int r = 0; r < 4; r++) {
#pragma unroll
          for (int t2 = 0; t2 < 2; t2++) {
            const int pxx = t2 * 16 + lm;
            lp[pxx * 100 + prow + r] += rnA[pxx] * acc[i][t2][r];
          }
        }
      }
    }
    __syncthreads();

    // ---- max over M ----
    for (int idx = tid; idx < TPX * K_; idx += 256) {
      const int pxx = idx / K_;
      const int k = idx - pxx * K_;
      const float* row = lp + pxx * 100 + k * M_;
      float mv = row[0];
#pragma unroll
      for (int m = 1; m < M_; m++) mv = fmaxf(mv, row[m]);
      mpr[pxx * 20 + k] = mv;
    }
    __syncthreads();
    // ---- LN over K (two-pass: values ~ -470, var ~ 1e-3) ----
    if (tid < 32) {
      float ss = 0.f;
      for (int k = 0; k < K_; k++) ss += mpr[tid * 20 + k];
      float m2 = ss * (1.f / K_);
      float qq = 0.f;
      for (int k = 0; k < K_; k++) {
        float d = mpr[tid * 20 + k] - m2;
        qq += d * d;
      }
      mean2A[tid] = m2;
      rstd2A[tid] = rsqrtf(qq * (1.f / K_) + 1e-5f);
    }
    __syncthreads();
    // ---- coalesced store (B,K,H,W); mgs/mbs from LDS (no vmem reads) ----
    float* obase = out + ((size_t)(b * K_) * 128 + h) * 128 + w0;
    for (int idx = tid; idx < TPX * K_; idx += 256) {
      const int k = idx >> 5, pxx = idx & 31;
      float v = fmaf((mpr[pxx * 20 + k] - mean2A[pxx]) * rstd2A[pxx], mgs[k], mbs[k]);
      obase[(size_t)k * HW_ + pxx] = v;
    }
    __syncthreads();  // protect raw/stat arrays before next tile's phase A
  }
}

extern "C" void kernel_launch(void* const* d_in, const int* in_sizes, int n_in,
                              void* d_out, int out_size, void* d_ws, size_t ws_size,
                              hipStream_t stream) {
  const float* x = (const float*)d_in[0];
  const float* means = (const float*)d_in[1];
  const float* diag = (const float*)d_in[2];
  const float* fg = (const float*)d_in[3];
  const float* fb = (const float*)d_in[4];
  const float* mg = (const float*)d_in[5];
  const float* mb = (const float*)d_in[6];
  float* out = (float*)d_out;

  short* wbf = (short*)d_ws;                                     // 96*1024*2 B
  float* cterm = (float*)((char*)d_ws + (size_t)P2 * 1024 * 2);  // +96*4 B

  prep_kernel<<<P2, 256, 0, stream>>>(means, diag, wbf, cterm);
  main_kernel<<<GRID_, 256, 0, stream>>>(x, fg, fb, mg, mb, wbf, cterm, out);
}